// Round 1
// 212.394 us; speedup vs baseline: 1.0354x; 1.0354x over previous
//
#include <hip/hip_runtime.h>
#include <hip/hip_bf16.h>

#define N_NODES 50000
#define N_EDGES 800000
#define IN_FEAT 256
#define UNITS   128

typedef unsigned short ushort_t;
typedef __bf16 bf16x8 __attribute__((ext_vector_type(8)));
typedef float  f32x4  __attribute__((ext_vector_type(4)));
typedef unsigned short ushort8 __attribute__((ext_vector_type(8)));

__device__ __forceinline__ ushort_t f2bf(float f) {
    unsigned u = __float_as_uint(f);
    u += 0x7fff + ((u >> 16) & 1);      // round-to-nearest-even
    return (ushort_t)(u >> 16);
}

// ---------------------------------------------------------------------------
// K0: Wt[n][k] = bf16(W[k][n])  (128 x 256 bf16, 64 KB) -- done once, tiny.
// Fused: also zeroes counts[0..M) (replaces the hipMemsetAsync dispatch).
// ---------------------------------------------------------------------------
__global__ __launch_bounds__(256) void prep_wt_zero(const float* __restrict__ W,
                                                    ushort_t* __restrict__ Wt,
                                                    int* __restrict__ counts, int M) {
    int i = blockIdx.x * 256 + threadIdx.x;
    if (i < UNITS * IN_FEAT) {
        int n = i >> 8;
        int k = i & 255;
        Wt[i] = f2bf(W[(size_t)k * UNITS + n]);
    }
    if (i < M) counts[i] = 0;
}

// ---------------------------------------------------------------------------
// K1: h(bf16) = A(50000x256 fp32 -> bf16) @ W via MFMA 16x16x32 bf16.
// BM=64, BN=128(full), BK=32. 256 thr = 4 waves in 2x2; wave tile 32x64.
// LDS row stride 40 bf16 (80B = 20 banks -> 2-way conflicts only, free).
// Fused epilogue: attention logits a_tgt/a_src computed from the f32
// accumulators (saves the 12.8 MB Hb re-read + one dispatch).
// ---------------------------------------------------------------------------
__global__ __launch_bounds__(256) void gemm_mfma(const float* __restrict__ A,
                                                 const ushort_t* __restrict__ Wt,
                                                 const float* __restrict__ ka,
                                                 ushort_t* __restrict__ Hb,
                                                 float* __restrict__ a_tgt,
                                                 float* __restrict__ a_src, int M) {
    __shared__ __align__(16) ushort_t As[64 * 40];    // 5 KB
    __shared__ __align__(16) ushort_t Bs[128 * 40];   // 10 KB
    __shared__ float spt[64][2];                      // 0.5 KB: per-row, per-wx
    __shared__ float sps[64][2];                      // 0.5 KB
    const int tid  = threadIdx.x;
    const int lane = tid & 63;
    const int wv   = tid >> 6;
    const int wy   = wv >> 1;          // 0..1 : row half
    const int wx   = wv & 1;           // 0..1 : col half
    const int row0 = blockIdx.x * 64;
    const int quad = lane >> 4;
    const int cl   = lane & 15;

    f32x4 acc[2][4] = {};

    const int ar = tid >> 2, aq = tid & 3;            // A: row, 8-col group
    const int gr = min(row0 + ar, M - 1);
    const float*    aptr   = A + (size_t)gr * IN_FEAT + aq * 8;
    ushort_t*       as_dst = As + ar * 40 + aq * 8;
    const int br = tid >> 1, bh = tid & 1;            // B: n-row, 16-col half
    const ushort_t* wptr   = Wt + br * IN_FEAT + bh * 16;
    ushort_t*       bs_dst = Bs + br * 40 + bh * 16;

    for (int kc = 0; kc < IN_FEAT; kc += 32) {
        float4 f0 = *(const float4*)(aptr + kc);
        float4 f1 = *(const float4*)(aptr + kc + 4);
        ushort8 w0 = *(const ushort8*)(wptr + kc);
        ushort8 w1 = *(const ushort8*)(wptr + kc + 8);
        ushort8 u;
        u[0] = f2bf(f0.x); u[1] = f2bf(f0.y); u[2] = f2bf(f0.z); u[3] = f2bf(f0.w);
        u[4] = f2bf(f1.x); u[5] = f2bf(f1.y); u[6] = f2bf(f1.z); u[7] = f2bf(f1.w);
        __syncthreads();
        *(ushort8*)as_dst = u;
        *(ushort8*)bs_dst        = w0;
        *(ushort8*)(bs_dst + 8)  = w1;
        __syncthreads();

        bf16x8 af[2], bff[4];
#pragma unroll
        for (int mi = 0; mi < 2; ++mi)
            af[mi] = *(const bf16x8*)(As + (wy * 32 + mi * 16 + cl) * 40 + quad * 8);
#pragma unroll
        for (int ni = 0; ni < 4; ++ni)
            bff[ni] = *(const bf16x8*)(Bs + (wx * 64 + ni * 16 + cl) * 40 + quad * 8);
#pragma unroll
        for (int mi = 0; mi < 2; ++mi)
#pragma unroll
            for (int ni = 0; ni < 4; ++ni)
                acc[mi][ni] = __builtin_amdgcn_mfma_f32_16x16x32_bf16(
                    af[mi], bff[ni], acc[mi][ni], 0, 0, 0);
    }

    // ---- Hb store (bf16) ----
#pragma unroll
    for (int mi = 0; mi < 2; ++mi) {
#pragma unroll
        for (int ni = 0; ni < 4; ++ni) {
            int col = wx * 64 + ni * 16 + cl;
#pragma unroll
            for (int r = 0; r < 4; ++r) {
                int row = row0 + wy * 32 + mi * 16 + quad * 4 + r;
                if (row < M)
                    Hb[(size_t)row * UNITS + col] = f2bf(acc[mi][ni][r]);
            }
        }
    }

    // ---- fused attention logits: a_tgt/a_src = acc . ka ----
    float kt[4], ks[4];
#pragma unroll
    for (int ni = 0; ni < 4; ++ni) {
        int col = wx * 64 + ni * 16 + cl;
        kt[ni] = ka[col];
        ks[ni] = ka[UNITS + col];
    }
#pragma unroll
    for (int mi = 0; mi < 2; ++mi) {
        float pt[4] = {}, ps[4] = {};
#pragma unroll
        for (int ni = 0; ni < 4; ++ni)
#pragma unroll
            for (int r = 0; r < 4; ++r) {
                pt[r] += acc[mi][ni][r] * kt[ni];
                ps[r] += acc[mi][ni][r] * ks[ni];
            }
#pragma unroll
        for (int r = 0; r < 4; ++r) {
            // reduce across the 16 cl-lanes (xor masks stay inside the quad)
#pragma unroll
            for (int m = 1; m < 16; m <<= 1) {
                pt[r] += __shfl_xor(pt[r], m);
                ps[r] += __shfl_xor(ps[r], m);
            }
            if (cl == 0) {
                int rl = wy * 32 + mi * 16 + quad * 4 + r;
                spt[rl][wx] = pt[r];
                sps[rl][wx] = ps[r];
            }
        }
    }
    __syncthreads();
    if (tid < 64) {
        int row = row0 + tid;
        if (row < M) {
            a_tgt[row] = spt[tid][0] + spt[tid][1];
            a_src[row] = sps[tid][0] + sps[tid][1];
        }
    }
}

__device__ __forceinline__ float edge_score(float at, float as) {
    float s = at + as;
    s = s > 0.f ? s : 0.2f * s;          // leaky_relu
    s = fminf(fmaxf(s, -2.f), 2.f);      // clip
    return __expf(s);
}

// ---------------------------------------------------------------------------
// K2: rank[e] = arrival index among edges with same tgt; counts histogram.
// ---------------------------------------------------------------------------
__global__ __launch_bounds__(256) void edge_rank(const int* __restrict__ edges,
                                                 int* __restrict__ counts,
                                                 int* __restrict__ rank_, int E) {
    int e = blockIdx.x * 256 + threadIdx.x;
    if (e >= E) return;
    int2 ts = ((const int2*)edges)[e];   // (tgt, src)
    rank_[e] = atomicAdd(&counts[ts.x], 1);
}

// ---------------------------------------------------------------------------
// K3: single-block single-pass scan. Each thread owns 52 contiguous counts
// (13x int4): local serial scan + one wave-scan + 16-entry combine.
// One barrier pair total (vs 13 chunks x 2 barriers before).
// ---------------------------------------------------------------------------
__global__ __launch_bounds__(1024) void scan_offsets(const int* __restrict__ counts,
                                                     int* __restrict__ offsets, int n) {
    __shared__ int wsum[16];
    __shared__ int total_sh;
    const int tid = threadIdx.x;
    const int lane = tid & 63, wid = tid >> 6;
    const int i0 = tid * 52;             // 1024 * 52 = 53248 >= n

    int4 c[13];
    int s = 0;
#pragma unroll
    for (int j = 0; j < 13; ++j) {
        int idx = i0 + j * 4;
        int4 v = make_int4(0, 0, 0, 0);
        if (idx + 3 < n) v = *(const int4*)(counts + idx);
        else if (idx < n) {
            v.x = counts[idx];
            if (idx + 1 < n) v.y = counts[idx + 1];
            if (idx + 2 < n) v.z = counts[idx + 2];
        }
        c[j] = v;
        s += v.x + v.y + v.z + v.w;
    }

    int incl = s;
#pragma unroll
    for (int off = 1; off < 64; off <<= 1) {
        int t = __shfl_up(incl, off);
        if (lane >= off) incl += t;
    }
    if (lane == 63) wsum[wid] = incl;
    __syncthreads();
    if (tid == 0) {
        int run = 0;
#pragma unroll
        for (int i = 0; i < 16; ++i) { int v = wsum[i]; wsum[i] = run; run += v; }
        total_sh = run;
    }
    __syncthreads();

    int run = wsum[wid] + (incl - s);    // exclusive prefix for this thread
#pragma unroll
    for (int j = 0; j < 13; ++j) {
        int idx = i0 + j * 4;
        int4 o;
        o.x = run; o.y = o.x + c[j].x; o.z = o.y + c[j].y; o.w = o.z + c[j].z;
        if (idx + 3 < n) *(int4*)(offsets + idx) = o;
        else if (idx < n) {
            offsets[idx] = o.x;
            if (idx + 1 < n) offsets[idx + 1] = o.y;
            if (idx + 2 < n) offsets[idx + 2] = o.z;
        }
        run = o.w + c[j].w;
    }
    if (tid == 0) offsets[n] = total_sh;
}

// ---------------------------------------------------------------------------
// K4: atomic-free CSR scatter; packed {src, score} int2 per entry.
// ---------------------------------------------------------------------------
__global__ __launch_bounds__(256) void build_csr(const int* __restrict__ edges,
                                                 const int* __restrict__ rank_,
                                                 const float* __restrict__ at,
                                                 const float* __restrict__ as,
                                                 const int* __restrict__ offsets,
                                                 int2* __restrict__ csr, int E) {
    int e = blockIdx.x * 256 + threadIdx.x;
    if (e >= E) return;
    int2 ts = ((const int2*)edges)[e];
    float sc = edge_score(at[ts.x], as[ts.y]);
    int pos = offsets[ts.x] + rank_[e];
    csr[pos] = make_int2(ts.y, __float_as_int(sc));
}

// ---------------------------------------------------------------------------
// K5: one wave per target node; 4 edge-slots x 16 feature-lanes.
// Lane g*16+c loads 16B (8 bf16) of h[src_g] -> one dwordx4 instruction
// covers 4 independent rows => ~4x shorter exposed-latency chain than a
// 1-row-per-step scheme (mean degree 16 -> 4 steps).
// ---------------------------------------------------------------------------
__global__ __launch_bounds__(256) void aggregate(const ushort_t* __restrict__ Hb,
                                                 const int* __restrict__ offsets,
                                                 const int2* __restrict__ csr,
                                                 float* __restrict__ out, int M) {
    int wid  = (int)((blockIdx.x * 256 + threadIdx.x) >> 6);
    int lane = threadIdx.x & 63;
    if (wid >= M) return;
    const int g = lane >> 4;            // edge slot 0..3
    const int c = lane & 15;            // feature chunk: feats [c*8, c*8+8)
    int beg = offsets[wid];
    int end = offsets[wid + 1];

    float acc[8] = {};
    float wacc = 0.f;

    for (int base = beg; base < end; base += 64) {
        int cd = min(64, end - base);
        int   s_v = 0;
        float w_v = 0.f;
        if (lane < cd) {
            int2 sw = csr[base + lane];
            s_v = sw.x;
            w_v = __int_as_float(sw.y);
        }
        wacc += w_v;                     // raw-score partial sum (whole wave)
        int nstep = (cd + 3) >> 2;
#pragma unroll 4
        for (int t = 0; t < nstep; ++t) {
            int slot = t * 4 + g;        // inactive slots: w=0, src=0 (safe)
            int   src = __shfl(s_v, slot);
            float w   = __shfl(w_v, slot);
            uint4 u = *(const uint4*)(Hb + (size_t)src * UNITS + c * 8);
            acc[0] += w * __uint_as_float(u.x << 16);
            acc[1] += w * __uint_as_float(u.x & 0xffff0000u);
            acc[2] += w * __uint_as_float(u.y << 16);
            acc[3] += w * __uint_as_float(u.y & 0xffff0000u);
            acc[4] += w * __uint_as_float(u.z << 16);
            acc[5] += w * __uint_as_float(u.z & 0xffff0000u);
            acc[6] += w * __uint_as_float(u.w << 16);
            acc[7] += w * __uint_as_float(u.w & 0xffff0000u);
        }
    }

    // combine the 4 edge-slot partials (lanes c, c+16, c+32, c+48)
#pragma unroll
    for (int i = 0; i < 8; ++i) {
        acc[i] += __shfl_xor(acc[i], 16);
        acc[i] += __shfl_xor(acc[i], 32);
    }
    // full-wave reduce of the raw-score sum -> denominator
#pragma unroll
    for (int off = 32; off > 0; off >>= 1) wacc += __shfl_xor(wacc, off);
    float scale = (end > beg) ? 1.0f / wacc : 0.0f;

    if (g == 0) {                        // 16 lanes x 32B = contiguous 512B
        float4 o0 = make_float4(acc[0] * scale, acc[1] * scale,
                                acc[2] * scale, acc[3] * scale);
        float4 o1 = make_float4(acc[4] * scale, acc[5] * scale,
                                acc[6] * scale, acc[7] * scale);
        float* dst = out + (size_t)wid * UNITS + c * 8;
        *(float4*)dst       = o0;
        *(float4*)(dst + 4) = o1;
    }
}

// ---------------------------------------------------------------------------
extern "C" void kernel_launch(void* const* d_in, const int* in_sizes, int n_in,
                              void* d_out, int out_size, void* d_ws, size_t ws_size,
                              hipStream_t stream) {
    const float* node_states = (const float*)d_in[0];
    const int*   edges       = (const int*)d_in[1];   // int32 pairs (tgt,src)
    const float* W           = (const float*)d_in[2];
    const float* ka          = (const float*)d_in[3];
    float*       out         = (float*)d_out;

    const int M = N_NODES, E = N_EDGES;

    // workspace layout (no trailing backslashes in comments!)
    ushort_t* hb     = (ushort_t*)d_ws;                // M*128 bf16 = 12.8 MB
    float*    a_tgt  = (float*)(hb + (size_t)M * UNITS); // M
    float*    a_src  = a_tgt + M;                      // M
    int*      counts = (int*)(a_src + M);              // M  -- zeroed by prep_wt_zero
    int*      offsets= counts + M;                     // M+2 (pad for int2 align)
    int*      rank_  = offsets + M + 2;                // E
    int2*     csr    = (int2*)(rank_ + E);             // E int2 (8B aligned)
    // Wt (64KB bf16) aliases csr storage: only used by prep_wt/gemm_mfma,
    // which complete before build_csr writes csr. Stream-ordered => safe.
    ushort_t* wt     = (ushort_t*)csr;

    prep_wt_zero<<<(M + 255) / 256, 256, 0, stream>>>(W, wt, counts, M);
    gemm_mfma   <<<(M + 63) / 64, 256, 0, stream>>>(node_states, wt, ka, hb,
                                                    a_tgt, a_src, M);
    edge_rank   <<<(E + 255) / 256, 256, 0, stream>>>(edges, counts, rank_, E);
    scan_offsets<<<1, 1024, 0, stream>>>(counts, offsets, M);
    build_csr   <<<(E + 255) / 256, 256, 0, stream>>>(edges, rank_, a_tgt, a_src,
                                                      offsets, csr, E);
    aggregate   <<<(M * 64 + 255) / 256, 256, 0, stream>>>(hb, offsets, csr, out, M);
}